// Round 6
// baseline (582.272 us; speedup 1.0000x reference)
//
#include <hip/hip_runtime.h>

// ---------------- common helpers ----------------

typedef __attribute__((ext_vector_type(8))) short s16x8;   // 8 x bf16 (4 VGPRs)
typedef __attribute__((ext_vector_type(4))) float f32x4;   // 16x16 MFMA accumulator

__device__ __forceinline__ unsigned short f2bf(float f) {
  union { float f; unsigned u; } v; v.f = f;
  unsigned r = v.u + 0x7fffu + ((v.u >> 16) & 1u);   // round-to-nearest-even
  return (unsigned short)(r >> 16);
}
__device__ __forceinline__ float bf2f(unsigned short h) {
  union { unsigned u; float f; } v; v.u = ((unsigned)h) << 16; return v.f;
}
__device__ __forceinline__ void gload_lds16(const void* g, void* l) {
  __builtin_amdgcn_global_load_lds(
      (const __attribute__((address_space(1))) void*)g,
      (__attribute__((address_space(3))) void*)l, 16, 0, 0);
}

// ---------------- fp32 -> bf16 convert (weights) ----------------

__global__ void conv_bf16(const float4* __restrict__ src, ushort4* __restrict__ dst, int n4) {
  int i = blockIdx.x * blockDim.x + threadIdx.x;
  if (i >= n4) return;
  float4 v = src[i];
  ushort4 o;
  o.x = f2bf(v.x); o.y = f2bf(v.y); o.z = f2bf(v.z); o.w = f2bf(v.w);
  dst[i] = o;
}

// ---------------- fused time-shift mix -> xk, xv, xr (bf16) ----------------

__global__ void prep_mix3(const float4* __restrict__ hidden,
                          const float4* __restrict__ tmk,
                          const float4* __restrict__ tmv,
                          const float4* __restrict__ tmr,
                          ushort4* __restrict__ xk, ushort4* __restrict__ xv,
                          ushort4* __restrict__ xr,
                          int S, int H4, long long total4) {
  long long i = (long long)blockIdx.x * blockDim.x + threadIdx.x;
  if (i >= total4) return;
  int h4 = (int)(i % H4);
  long long sb = i / H4;          // b*S + s
  int s = (int)(sb % S);
  float4 cur = hidden[i];
  float4 prev = make_float4(0.f, 0.f, 0.f, 0.f);
  if (s > 0) prev = hidden[i - H4];
  float4 mk = tmk[h4], mv = tmv[h4], mr = tmr[h4];
  ushort4 ok, ov, orr;
  ok.x = f2bf(cur.x * mk.x + prev.x * (1.f - mk.x));
  ok.y = f2bf(cur.y * mk.y + prev.y * (1.f - mk.y));
  ok.z = f2bf(cur.z * mk.z + prev.z * (1.f - mk.z));
  ok.w = f2bf(cur.w * mk.w + prev.w * (1.f - mk.w));
  ov.x = f2bf(cur.x * mv.x + prev.x * (1.f - mv.x));
  ov.y = f2bf(cur.y * mv.y + prev.y * (1.f - mv.y));
  ov.z = f2bf(cur.z * mv.z + prev.z * (1.f - mv.z));
  ov.w = f2bf(cur.w * mv.w + prev.w * (1.f - mv.w));
  orr.x = f2bf(cur.x * mr.x + prev.x * (1.f - mr.x));
  orr.y = f2bf(cur.y * mr.y + prev.y * (1.f - mr.y));
  orr.z = f2bf(cur.z * mr.z + prev.z * (1.f - mr.z));
  orr.w = f2bf(cur.w * mr.w + prev.w * (1.f - mr.w));
  xk[i] = ok; xv[i] = ov; xr[i] = orr;
}

// ---------------- bf16 NT GEMM: C[M,N] = A[M,K] * B[N,K]^T ----------------
// NEW geometry this round: 128x256 tile, BK=32, ring-3 LDS (72 KiB) ->
// grid 512 blocks = 2 BLOCKS/CU co-resident + 2 dispatch rounds.
// Rationale: totals r1/r2/r3/r5 within 1.3% across four schedules at
// 1 block/CU + single-round grids => schedule-invariant bottleneck =
// no cross-block overlap (m114) + exposed prologue/epilogue bursts.
// 2 blocks/CU: one block's barrier/vmcnt stalls are covered by the other;
// 2 rounds: round-1 epilogue C-write bursts overlap round-2 compute.
// Everything else carried verbatim from r5 (harness-verified): 16x16x32
// MFMA frag + C/D mapping, zero-conflict swizzle pair (SQ_LDS_BANK_CONFLICT
// = 0 in r5), gload_lds linear staging, counted-vmcnt ring.
// Per tile (one phase): read 8 ds_read_b128 (a[4],b[4]) | STAGE(t+2)
// (3 gload_lds: A 1, B 2) | vmcnt(3) | barrier | lgkmcnt(0) | sched_bar |
// setprio(1) 16 MFMA setprio(0) | barrier.
// vmcnt(3): after STAGE(t+2), outstanding = tiles t+1 (3) + t+2 (3);
// vmcnt(3) retires tile t+1 -> landed before iter t+1 reads it (all waves
// pass their own vmcnt before barrier-2). Drain: t+2==NT -> vmcnt(0).
// Ring-3 WAR: STAGE slot (t+2)%3 = (t-1)%3 issues after barrier-2 of iter
// t-1, which follows lgkmcnt(0)-completed reads of tile t-1 in every wave.
// 8 waves = 2M x 4N, per-wave 64x64 = 4x4 16x16 frags (16 accs, ~120 VGPR,
// launch_bounds(512,4) => 4 waves/SIMD = 2 blocks/CU; LDS 2x72 = 144 <= 160).
// EPI: 0 = fp32; 1 = sigmoid bf16; 2 = bf16.

template <int EPI>
__global__ __launch_bounds__(512, 4) void gemm_bt(
    const unsigned short* __restrict__ A, const unsigned short* __restrict__ B,
    float* __restrict__ Cf, unsigned short* __restrict__ Cb,
    int M, int N, int K) {
  // 3 ring slots x (A 128x32 = 4096 shorts | B 256x32 = 8192 shorts) = 72 KiB
  __shared__ unsigned short lds[3 * 12288];

  const int tid = threadIdx.x;
  const int wave = tid >> 6;
  const int lane = tid & 63;

  // XCD-aware bijective block swizzle: nwg % 8 == 0 (512 blocks). Each XCD's
  // contiguous wg-run shares one 1-MiB B panel (L2-resident).
  const int nwg = (int)gridDim.x;
  const int q = nwg >> 3;
  const int wg = (blockIdx.x & 7) * q + (blockIdx.x >> 3);
  const int GM = M >> 7;               // M/128
  const int bm = (wg % GM) * 128;
  const int bn = (wg / GM) * 256;

  const int wm = (wave >> 2) * 64;     // wave's 64x64 sub-tile
  const int wn = (wave & 3) * 64;
  const int l15 = lane & 15;           // frag row within 16
  const int lg = lane >> 4;            // k-group (0..3)

  f32x4 acc[4][4] = {};                // 4 m-frags x 4 n-frags

  // ---- staging addresses (A: 1 gload/thread, B: 2 gloads/thread) ----
  // dest (linear): wave w covers 16 rows x 64B; lane l -> row w*16+(l>>2),
  // chunk l&3. Inverse swizzle on the GLOBAL source: src chunk =
  // (t&3) ^ ((row>>1)&3)  (row+128 preserves the pattern).
  const int srow = tid >> 2;
  const int sg = ((tid & 3) ^ ((srow >> 1) & 3)) * 8;
  const unsigned short* gA  = A + (long long)(bm + srow) * K + sg;
  const unsigned short* gB0 = B + (long long)(bn + srow) * K + sg;
  const unsigned short* gB1 = B + (long long)(bn + 128 + srow) * K + sg;

#define STAGE(sl)                                              \
  {                                                            \
    unsigned short* d = lds + (sl) * 12288 + wave * 512;       \
    gload_lds16(gA, d);                                        \
    gload_lds16(gB0, d + 4096);                                \
    gload_lds16(gB1, d + 8192);                                \
    gA += 32; gB0 += 32; gB1 += 32;                            \
  }

  // ---- fragment LDS offsets (shorts; loop-invariant; r5-verified form) ----
  // row R, k-group g -> R*32 + ((g ^ ((R>>1)&3)) * 8); B region at +4096.
  int offA[4], offB[4];
#pragma unroll
  for (int mi = 0; mi < 4; ++mi) {
    int R = wm + mi * 16 + l15;
    offA[mi] = R * 32 + ((lg ^ ((R >> 1) & 3)) * 8);
  }
#pragma unroll
  for (int ni = 0; ni < 4; ++ni) {
    int R = wn + ni * 16 + l15;
    offB[ni] = 4096 + R * 32 + ((lg ^ ((R >> 1) & 3)) * 8);
  }

  const int NT = K >> 5;   // K/32 (= 64 here; >= 3 required)

  // ---- prologue: stage tiles 0,1; tile 0 landed (3 in flight) ----
  STAGE(0);
  STAGE(1);
  asm volatile("s_waitcnt vmcnt(3)" ::: "memory");
  __builtin_amdgcn_sched_barrier(0);
  __builtin_amdgcn_s_barrier();

  int sl0 = 0, sl1 = 1, sl2 = 2;       // slots of tiles t, t+1, t+2
  for (int t = 0; t < NT; ++t) {
    const unsigned short* sb = lds + sl0 * 12288;
    s16x8 a[4], b[4];
#pragma unroll
    for (int mi = 0; mi < 4; ++mi) a[mi] = *(const s16x8*)(sb + offA[mi]);
#pragma unroll
    for (int ni = 0; ni < 4; ++ni) b[ni] = *(const s16x8*)(sb + offB[ni]);

    if (t + 2 < NT) {
      STAGE(sl2);
      asm volatile("s_waitcnt vmcnt(3)" ::: "memory");   // tile t+1 landed
    } else if (t + 2 == NT) {
      asm volatile("s_waitcnt vmcnt(0)" ::: "memory");   // drain: last tile
    }
    __builtin_amdgcn_sched_barrier(0);
    __builtin_amdgcn_s_barrier();
    asm volatile("s_waitcnt lgkmcnt(0)" ::: "memory");
    __builtin_amdgcn_sched_barrier(0);

    __builtin_amdgcn_s_setprio(1);
#pragma unroll
    for (int mi = 0; mi < 4; ++mi)
#pragma unroll
      for (int ni = 0; ni < 4; ++ni)
        acc[mi][ni] = __builtin_amdgcn_mfma_f32_16x16x32_bf16(
            a[mi], b[ni], acc[mi][ni], 0, 0, 0);
    __builtin_amdgcn_s_setprio(0);
    __builtin_amdgcn_sched_barrier(0);
    __builtin_amdgcn_s_barrier();

    int tmp = sl0; sl0 = sl1; sl1 = sl2; sl2 = tmp;
  }
#undef STAGE

  // epilogue: 16x16 C/D layout col = lane&15, row = (lane>>4)*4 + reg
#pragma unroll
  for (int mi = 0; mi < 4; ++mi)
#pragma unroll
    for (int ni = 0; ni < 4; ++ni)
#pragma unroll
      for (int r = 0; r < 4; ++r) {
        int row = bm + wm + mi * 16 + lg * 4 + r;
        int col = bn + wn + ni * 16 + l15;
        float v = acc[mi][ni][r];
        long long idx = (long long)row * N + col;
        if (EPI == 0) {
          Cf[idx] = v;
        } else if (EPI == 1) {
          float s = 1.f / (1.f + __expf(-v));
          Cb[idx] = f2bf(s);
        } else {
          Cb[idx] = f2bf(v);
        }
      }
}

// ---------------- chunked WKV scan (bf16 k/v/r), x4 vectorized ----------------

#define NEG_INF_F (-1e38f)

__global__ void scan_phase1(const ushort4* __restrict__ kb,
                            const ushort4* __restrict__ vb,
                            const float4* __restrict__ td,
                            float4* __restrict__ locN, float4* __restrict__ locD,
                            float4* __restrict__ locM,
                            int S, int D4, int C, int L) {
  int t = blockIdx.x * blockDim.x + threadIdx.x;  // over B*C*D4
  int d = t % D4;
  int c = (t / D4) % C;
  int b = t / (D4 * C);
  float4 tdv = td[d];
  float w[4] = {-__expf(tdv.x), -__expf(tdv.y), -__expf(tdv.z), -__expf(tdv.w)};
  float num[4] = {0.f, 0.f, 0.f, 0.f}, den[4] = {0.f, 0.f, 0.f, 0.f};
  float m[4] = {NEG_INF_F, NEG_INF_F, NEG_INF_F, NEG_INF_F};
  long long base = (long long)(b * S + c * L) * D4 + d;
  ushort4 k0 = kb[base], v0 = vb[base];
  for (int i = 0; i < L; ++i) {
    ushort4 k1, v1;
    if (i + 1 < L) { k1 = kb[base + D4]; v1 = vb[base + D4]; }
    float kk[4] = {bf2f(k0.x), bf2f(k0.y), bf2f(k0.z), bf2f(k0.w)};
    float vv[4] = {bf2f(v0.x), bf2f(v0.y), bf2f(v0.z), bf2f(v0.w)};
#pragma unroll
    for (int j = 0; j < 4; ++j) {
      float mn = fmaxf(m[j] + w[j], kk[j]);
      float e1 = __expf(m[j] + w[j] - mn);
      float e2 = __expf(kk[j] - mn);
      num[j] = e1 * num[j] + e2 * vv[j];
      den[j] = e1 * den[j] + e2;
      m[j] = mn;
    }
    k0 = k1; v0 = v1; base += D4;
  }
  int o = (b * C + c) * D4 + d;
  locN[o] = make_float4(num[0], num[1], num[2], num[3]);
  locD[o] = make_float4(den[0], den[1], den[2], den[3]);
  locM[o] = make_float4(m[0], m[1], m[2], m[3]);
}

__global__ void scan_phase2(const float4* __restrict__ td,
                            const float4* __restrict__ locN, const float4* __restrict__ locD,
                            const float4* __restrict__ locM,
                            float4* __restrict__ inN, float4* __restrict__ inD,
                            float4* __restrict__ inM,
                            int Bc, int D4, int C, int L) {
  int t = blockIdx.x * blockDim.x + threadIdx.x;  // over B*D4
  if (t >= Bc * D4) return;
  int d = t % D4, b = t / D4;
  float4 tdv = td[d];
  float w[4] = {-__expf(tdv.x), -__expf(tdv.y), -__expf(tdv.z), -__expf(tdv.w)};
  float num[4] = {0.f, 0.f, 0.f, 0.f}, den[4] = {0.f, 0.f, 0.f, 0.f};
  float m[4] = {NEG_INF_F, NEG_INF_F, NEG_INF_F, NEG_INF_F};
  for (int c = 0; c < C; ++c) {
    int o = (b * C + c) * D4 + d;
    inN[o] = make_float4(num[0], num[1], num[2], num[3]);
    inD[o] = make_float4(den[0], den[1], den[2], den[3]);
    inM[o] = make_float4(m[0], m[1], m[2], m[3]);
    float4 lN = locN[o], lD = locD[o], lM = locM[o];
    float lNa[4] = {lN.x, lN.y, lN.z, lN.w};
    float lDa[4] = {lD.x, lD.y, lD.z, lD.w};
    float lMa[4] = {lM.x, lM.y, lM.z, lM.w};
#pragma unroll
    for (int j = 0; j < 4; ++j) {
      float sm = m[j] + (float)L * w[j];
      float m2 = fmaxf(sm, lMa[j]);
      float e1 = __expf(sm - m2);
      float e2 = __expf(lMa[j] - m2);
      num[j] = e1 * num[j] + e2 * lNa[j];
      den[j] = e1 * den[j] + e2 * lDa[j];
      m[j] = m2;
    }
  }
}

__global__ void scan_phase3(const ushort4* __restrict__ kb,
                            const ushort4* __restrict__ vb,
                            const ushort4* __restrict__ rb,
                            const float4* __restrict__ td, const float4* __restrict__ tfirst,
                            const float4* __restrict__ inN, const float4* __restrict__ inD,
                            const float4* __restrict__ inM,
                            ushort4* __restrict__ rr,
                            int S, int D4, int C, int L) {
  int t = blockIdx.x * blockDim.x + threadIdx.x;  // over B*C*D4
  int d = t % D4;
  int c = (t / D4) % C;
  int b = t / (D4 * C);
  float4 tdv = td[d], tfv = tfirst[d];
  float w[4] = {-__expf(tdv.x), -__expf(tdv.y), -__expf(tdv.z), -__expf(tdv.w)};
  float tf[4] = {tfv.x, tfv.y, tfv.z, tfv.w};
  int o = (b * C + c) * D4 + d;
  float4 N0 = inN[o], D0 = inD[o], M0 = inM[o];
  float num[4] = {N0.x, N0.y, N0.z, N0.w};
  float den[4] = {D0.x, D0.y, D0.z, D0.w};
  float m[4] = {M0.x, M0.y, M0.z, M0.w};
  long long base = (long long)(b * S + c * L) * D4 + d;
  ushort4 k0 = kb[base], v0 = vb[base], r0 = rb[base];
  for (int i = 0; i < L; ++i) {
    ushort4 k1, v1, r1;
    if (i + 1 < L) { k1 = kb[base + D4]; v1 = vb[base + D4]; r1 = rb[base + D4]; }
    float kk[4] = {bf2f(k0.x), bf2f(k0.y), bf2f(k0.z), bf2f(k0.w)};
    float vv[4] = {bf2f(v0.x), bf2f(v0.y), bf2f(v0.z), bf2f(v0.w)};
    float rv[4] = {bf2f(r0.x), bf2f(r0.y), bf2f(r0.z), bf2f(r0.w)};
    unsigned short ov[4];
#pragma unroll
    for (int j = 0; j < 4; ++j) {
      float ktf = kk[j] + tf[j];
      float mo = fmaxf(m[j], ktf);
      float e1 = __expf(m[j] - mo);
      float e2 = __expf(ktf - mo);
      float out = (e1 * num[j] + e2 * vv[j]) / (e1 * den[j] + e2);
      ov[j] = f2bf(out * rv[j]);
      float mn = fmaxf(m[j] + w[j], kk[j]);
      e1 = __expf(m[j] + w[j] - mn);
      e2 = __expf(kk[j] - mn);
      num[j] = e1 * num[j] + e2 * vv[j];
      den[j] = e1 * den[j] + e2;
      m[j] = mn;
    }
    ushort4 ow; ow.x = ov[0]; ow.y = ov[1]; ow.z = ov[2]; ow.w = ov[3];
    rr[base] = ow;
    k0 = k1; v0 = v1; r0 = r1; base += D4;
  }
}

// ---------------- launch ----------------

extern "C" void kernel_launch(void* const* d_in, const int* in_sizes, int n_in,
                              void* d_out, int out_size, void* d_ws, size_t ws_size,
                              hipStream_t stream) {
  const float* hidden = (const float*)d_in[0];
  const float* td  = (const float*)d_in[1];
  const float* tfi = (const float*)d_in[2];
  const float* tmk = (const float*)d_in[3];
  const float* tmv = (const float*)d_in[4];
  const float* tmr = (const float*)d_in[5];
  const float* Wk  = (const float*)d_in[6];
  const float* Wv  = (const float*)d_in[7];
  const float* Wr  = (const float*)d_in[8];
  const float* Wo  = (const float*)d_in[9];
  float* out = (float*)d_out;

  const int H = in_sizes[1];                 // 2048
  const int D = H;
  const long long BS = (long long)in_sizes[0] / H;  // 8192 = B*S
  const int S = 2048;
  const int B = (int)(BS / S);               // 4
  const int C = 32, L = S / C;               // 32 chunks of 64
  const int D4 = D / 4;

  // workspace layout (110 MiB, proven safe):
  //   W_b [0,8) | X [8,40) | Y [40,72) | Z [72,104) | states [104,110)
  char* ws = (char*)d_ws;
  const size_t MB = 1u << 20;
  unsigned short* W_b = (unsigned short*)(ws + 0 * MB);
  unsigned short* X   = (unsigned short*)(ws + 8 * MB);
  unsigned short* Y   = (unsigned short*)(ws + 40 * MB);
  unsigned short* Z   = (unsigned short*)(ws + 72 * MB);
  float* locN         = (float*)(ws + 104 * MB);
  float* locD         = (float*)(ws + 105 * MB);
  float* locM         = (float*)(ws + 106 * MB);
  float* inN          = (float*)(ws + 107 * MB);
  float* inD          = (float*)(ws + 108 * MB);
  float* inM          = (float*)(ws + 109 * MB);
  unsigned short* kb  = (unsigned short*)out;   // bf16 k scratch in d_out

  int n4w = H * H / 4;
  int cbk = (n4w + 255) / 256;
  long long total4 = BS * H / 4;
  int pbk = (int)((total4 + 255) / 256);
  int nwg = (int)((BS / 128) * (D / 256));   // 64 * 8 = 512 blocks, 2/CU

  // fused time-shift mix (one pass over hidden)
  prep_mix3<<<pbk, 256, 0, stream>>>((const float4*)hidden,
                                     (const float4*)tmk, (const float4*)tmv, (const float4*)tmr,
                                     (ushort4*)X, (ushort4*)Y, (ushort4*)Z, S, H / 4, total4);

  // k = xk @ Wk^T  (bf16 -> d_out scratch)
  conv_bf16<<<cbk, 256, 0, stream>>>((const float4*)Wk, (ushort4*)W_b, n4w);
  gemm_bt<2><<<nwg, 512, 0, stream>>>(X, W_b, nullptr, kb, (int)BS, D, H);

  // v = xv @ Wv^T  (bf16 -> X)
  conv_bf16<<<cbk, 256, 0, stream>>>((const float4*)Wv, (ushort4*)W_b, n4w);
  gemm_bt<2><<<nwg, 512, 0, stream>>>(Y, W_b, nullptr, X, (int)BS, D, H);

  // r = sigmoid(xr @ Wr^T)  (bf16 -> Y)
  conv_bf16<<<cbk, 256, 0, stream>>>((const float4*)Wr, (ushort4*)W_b, n4w);
  gemm_bt<1><<<nwg, 512, 0, stream>>>(Z, W_b, nullptr, Y, (int)BS, D, H);

  // chunked WKV scan (x4 vectorized), fused r * rwkv -> Z (bf16)
  int nscan4 = B * C * D4;                   // 65536
  scan_phase1<<<nscan4 / 256, 256, 0, stream>>>(
      (const ushort4*)kb, (const ushort4*)X, (const float4*)td,
      (float4*)locN, (float4*)locD, (float4*)locM, S, D4, C, L);
  scan_phase2<<<(B * D4 + 255) / 256, 256, 0, stream>>>(
      (const float4*)td, (const float4*)locN, (const float4*)locD, (const float4*)locM,
      (float4*)inN, (float4*)inD, (float4*)inM, B, D4, C, L);
  scan_phase3<<<nscan4 / 256, 256, 0, stream>>>(
      (const ushort4*)kb, (const ushort4*)X, (const ushort4*)Y,
      (const float4*)td, (const float4*)tfi,
      (const float4*)inN, (const float4*)inD, (const float4*)inM,
      (ushort4*)Z, S, D4, C, L);

  // out = (r * rwkv) @ Wo^T  (fp32 -> d_out; kb dead now)
  conv_bf16<<<cbk, 256, 0, stream>>>((const float4*)Wo, (ushort4*)W_b, n4w);
  gemm_bt<0><<<nwg, 512, 0, stream>>>(Z, W_b, out, nullptr, (int)BS, H, D);
}

// Round 7
// 560.647 us; speedup vs baseline: 1.0386x; 1.0386x over previous
//
#include <hip/hip_runtime.h>

// ---------------- common helpers ----------------

typedef __attribute__((ext_vector_type(8))) short s16x8;   // 8 x bf16 (4 VGPRs)
typedef __attribute__((ext_vector_type(4))) float f32x4;   // 16x16 MFMA accumulator

__device__ __forceinline__ unsigned short f2bf(float f) {
  union { float f; unsigned u; } v; v.f = f;
  unsigned r = v.u + 0x7fffu + ((v.u >> 16) & 1u);   // round-to-nearest-even
  return (unsigned short)(r >> 16);
}
__device__ __forceinline__ float bf2f(unsigned short h) {
  union { unsigned u; float f; } v; v.u = ((unsigned)h) << 16; return v.f;
}
__device__ __forceinline__ void gload_lds16(const void* g, void* l) {
  __builtin_amdgcn_global_load_lds(
      (const __attribute__((address_space(1))) void*)g,
      (__attribute__((address_space(3))) void*)l, 16, 0, 0);
}

// ---------------- fp32 -> bf16 convert: ALL 4 weights, one dispatch ----------

__global__ void conv_bf16_4(const float4* __restrict__ w0,
                            const float4* __restrict__ w1,
                            const float4* __restrict__ w2,
                            const float4* __restrict__ w3,
                            ushort4* __restrict__ dst, int n4) {
  int i = blockIdx.x * blockDim.x + threadIdx.x;
  if (i >= n4) return;
  int w = blockIdx.y;
  const float4* src = (w == 0) ? w0 : (w == 1) ? w1 : (w == 2) ? w2 : w3;
  float4 v = src[i];
  ushort4 o;
  o.x = f2bf(v.x); o.y = f2bf(v.y); o.z = f2bf(v.z); o.w = f2bf(v.w);
  dst[(long long)w * n4 + i] = o;
}

// ---------------- fused time-shift mix -> xk, xv, xr (bf16) ----------------

__global__ void prep_mix3(const float4* __restrict__ hidden,
                          const float4* __restrict__ tmk,
                          const float4* __restrict__ tmv,
                          const float4* __restrict__ tmr,
                          ushort4* __restrict__ xk, ushort4* __restrict__ xv,
                          ushort4* __restrict__ xr,
                          int S, int H4, long long total4) {
  long long i = (long long)blockIdx.x * blockDim.x + threadIdx.x;
  if (i >= total4) return;
  int h4 = (int)(i % H4);
  long long sb = i / H4;          // b*S + s
  int s = (int)(sb % S);
  float4 cur = hidden[i];
  float4 prev = make_float4(0.f, 0.f, 0.f, 0.f);
  if (s > 0) prev = hidden[i - H4];
  float4 mk = tmk[h4], mv = tmv[h4], mr = tmr[h4];
  ushort4 ok, ov, orr;
  ok.x = f2bf(cur.x * mk.x + prev.x * (1.f - mk.x));
  ok.y = f2bf(cur.y * mk.y + prev.y * (1.f - mk.y));
  ok.z = f2bf(cur.z * mk.z + prev.z * (1.f - mk.z));
  ok.w = f2bf(cur.w * mk.w + prev.w * (1.f - mk.w));
  ov.x = f2bf(cur.x * mv.x + prev.x * (1.f - mv.x));
  ov.y = f2bf(cur.y * mv.y + prev.y * (1.f - mv.y));
  ov.z = f2bf(cur.z * mv.z + prev.z * (1.f - mv.z));
  ov.w = f2bf(cur.w * mv.w + prev.w * (1.f - mv.w));
  orr.x = f2bf(cur.x * mr.x + prev.x * (1.f - mr.x));
  orr.y = f2bf(cur.y * mr.y + prev.y * (1.f - mr.y));
  orr.z = f2bf(cur.z * mr.z + prev.z * (1.f - mr.z));
  orr.w = f2bf(cur.w * mr.w + prev.w * (1.f - mr.w));
  xk[i] = ok; xv[i] = ov; xr[i] = orr;
}

// ---------------- bf16 NT GEMM: C[M,N] = A[M,K] * B[N,K]^T ----------------
// r6 kernel verbatim (control group this round): 128x256 tile, BK=32, ring-3
// LDS (72 KiB), grid 512 = 2 blocks/CU, zero bank conflicts, counted vmcnt.
// Per tile: read 8 ds_read_b128 | STAGE(t+2) (3 gload_lds) | vmcnt(3) |
// barrier | lgkmcnt(0) | setprio(1) 16 MFMA setprio(0) | barrier.
// EPI: 0 = fp32; 1 = sigmoid bf16; 2 = bf16.

template <int EPI>
__global__ __launch_bounds__(512, 4) void gemm_bt(
    const unsigned short* __restrict__ A, const unsigned short* __restrict__ B,
    float* __restrict__ Cf, unsigned short* __restrict__ Cb,
    int M, int N, int K) {
  // 3 ring slots x (A 128x32 = 4096 shorts | B 256x32 = 8192 shorts) = 72 KiB
  __shared__ unsigned short lds[3 * 12288];

  const int tid = threadIdx.x;
  const int wave = tid >> 6;
  const int lane = tid & 63;

  // XCD-aware bijective block swizzle: nwg % 8 == 0 (512 blocks).
  const int nwg = (int)gridDim.x;
  const int q = nwg >> 3;
  const int wg = (blockIdx.x & 7) * q + (blockIdx.x >> 3);
  const int GM = M >> 7;               // M/128
  const int bm = (wg % GM) * 128;
  const int bn = (wg / GM) * 256;

  const int wm = (wave >> 2) * 64;     // wave's 64x64 sub-tile
  const int wn = (wave & 3) * 64;
  const int l15 = lane & 15;           // frag row within 16
  const int lg = lane >> 4;            // k-group (0..3)

  f32x4 acc[4][4] = {};                // 4 m-frags x 4 n-frags

  // ---- staging addresses (A: 1 gload/thread, B: 2 gloads/thread) ----
  const int srow = tid >> 2;
  const int sg = ((tid & 3) ^ ((srow >> 1) & 3)) * 8;
  const unsigned short* gA  = A + (long long)(bm + srow) * K + sg;
  const unsigned short* gB0 = B + (long long)(bn + srow) * K + sg;
  const unsigned short* gB1 = B + (long long)(bn + 128 + srow) * K + sg;

#define STAGE(sl)                                              \
  {                                                            \
    unsigned short* d = lds + (sl) * 12288 + wave * 512;       \
    gload_lds16(gA, d);                                        \
    gload_lds16(gB0, d + 4096);                                \
    gload_lds16(gB1, d + 8192);                                \
    gA += 32; gB0 += 32; gB1 += 32;                            \
  }

  // ---- fragment LDS offsets (shorts; loop-invariant) ----
  // row R, k-group g -> R*32 + ((g ^ ((R>>1)&3)) * 8); B region at +4096.
  int offA[4], offB[4];
#pragma unroll
  for (int mi = 0; mi < 4; ++mi) {
    int R = wm + mi * 16 + l15;
    offA[mi] = R * 32 + ((lg ^ ((R >> 1) & 3)) * 8);
  }
#pragma unroll
  for (int ni = 0; ni < 4; ++ni) {
    int R = wn + ni * 16 + l15;
    offB[ni] = 4096 + R * 32 + ((lg ^ ((R >> 1) & 3)) * 8);
  }

  const int NT = K >> 5;   // K/32 (= 64 here; >= 3 required)

  // ---- prologue: stage tiles 0,1; tile 0 landed (3 in flight) ----
  STAGE(0);
  STAGE(1);
  asm volatile("s_waitcnt vmcnt(3)" ::: "memory");
  __builtin_amdgcn_sched_barrier(0);
  __builtin_amdgcn_s_barrier();

  int sl0 = 0, sl1 = 1, sl2 = 2;       // slots of tiles t, t+1, t+2
  for (int t = 0; t < NT; ++t) {
    const unsigned short* sb = lds + sl0 * 12288;
    s16x8 a[4], b[4];
#pragma unroll
    for (int mi = 0; mi < 4; ++mi) a[mi] = *(const s16x8*)(sb + offA[mi]);
#pragma unroll
    for (int ni = 0; ni < 4; ++ni) b[ni] = *(const s16x8*)(sb + offB[ni]);

    if (t + 2 < NT) {
      STAGE(sl2);
      asm volatile("s_waitcnt vmcnt(3)" ::: "memory");   // tile t+1 landed
    } else if (t + 2 == NT) {
      asm volatile("s_waitcnt vmcnt(0)" ::: "memory");   // drain: last tile
    }
    __builtin_amdgcn_sched_barrier(0);
    __builtin_amdgcn_s_barrier();
    asm volatile("s_waitcnt lgkmcnt(0)" ::: "memory");
    __builtin_amdgcn_sched_barrier(0);

    __builtin_amdgcn_s_setprio(1);
#pragma unroll
    for (int mi = 0; mi < 4; ++mi)
#pragma unroll
      for (int ni = 0; ni < 4; ++ni)
        acc[mi][ni] = __builtin_amdgcn_mfma_f32_16x16x32_bf16(
            a[mi], b[ni], acc[mi][ni], 0, 0, 0);
    __builtin_amdgcn_s_setprio(0);
    __builtin_amdgcn_sched_barrier(0);
    __builtin_amdgcn_s_barrier();

    int tmp = sl0; sl0 = sl1; sl1 = sl2; sl2 = tmp;
  }
#undef STAGE

  // epilogue: 16x16 C/D layout col = lane&15, row = (lane>>4)*4 + reg
#pragma unroll
  for (int mi = 0; mi < 4; ++mi)
#pragma unroll
    for (int ni = 0; ni < 4; ++ni)
#pragma unroll
      for (int r = 0; r < 4; ++r) {
        int row = bm + wm + mi * 16 + lg * 4 + r;
        int col = bn + wn + ni * 16 + l15;
        float v = acc[mi][ni][r];
        long long idx = (long long)row * N + col;
        if (EPI == 0) {
          Cf[idx] = v;
        } else if (EPI == 1) {
          float s = 1.f / (1.f + __expf(-v));
          Cb[idx] = f2bf(s);
        } else {
          Cb[idx] = f2bf(v);
        }
      }
}

// ---------------- chunked WKV scan (bf16 k/v/r), scalar r5 form ----------------

#define NEG_INF_F (-1e38f)

__global__ void scan_phase1(const unsigned short* __restrict__ kb,
                            const unsigned short* __restrict__ vb,
                            const float* __restrict__ td,
                            float* __restrict__ locN, float* __restrict__ locD,
                            float* __restrict__ locM,
                            int S, int D, int C, int L) {
  int t = blockIdx.x * blockDim.x + threadIdx.x;  // over B*C*D
  int d = t % D;
  int c = (t / D) % C;
  int b = t / (D * C);
  float w = -__expf(td[d]);
  float num = 0.f, den = 0.f, m = NEG_INF_F;
  long long base = ((long long)(b * S + c * L)) * D + d;
  for (int i = 0; i < L; ++i) {
    float kk = bf2f(kb[base]);
    float vv = bf2f(vb[base]);
    base += D;
    float mn = fmaxf(m + w, kk);
    float e1 = __expf(m + w - mn);
    float e2 = __expf(kk - mn);
    num = e1 * num + e2 * vv;
    den = e1 * den + e2;
    m = mn;
  }
  int o = (b * C + c) * D + d;
  locN[o] = num; locD[o] = den; locM[o] = m;
}

__global__ void scan_phase2(const float* __restrict__ td,
                            const float* __restrict__ locN, const float* __restrict__ locD,
                            const float* __restrict__ locM,
                            float* __restrict__ inN, float* __restrict__ inD,
                            float* __restrict__ inM,
                            int Bc, int D, int C, int L) {
  int t = blockIdx.x * blockDim.x + threadIdx.x;  // over B*D
  if (t >= Bc * D) return;
  int d = t % D, b = t / D;
  float w = -__expf(td[d]);
  float Lw = (float)L * w;
  float num = 0.f, den = 0.f, m = NEG_INF_F;
  for (int c = 0; c < C; ++c) {
    int o = (b * C + c) * D + d;
    inN[o] = num; inD[o] = den; inM[o] = m;
    float sm = m + Lw;                 // decay incoming state over whole chunk
    float lm = locM[o];
    float m2 = fmaxf(sm, lm);
    float e1 = __expf(sm - m2);
    float e2 = __expf(lm - m2);
    num = e1 * num + e2 * locN[o];
    den = e1 * den + e2 * locD[o];
    m = m2;
  }
}

__global__ void scan_phase3(const unsigned short* __restrict__ kb,
                            const unsigned short* __restrict__ vb,
                            const unsigned short* __restrict__ rb,
                            const float* __restrict__ td, const float* __restrict__ tfirst,
                            const float* __restrict__ inN, const float* __restrict__ inD,
                            const float* __restrict__ inM,
                            unsigned short* __restrict__ rr,
                            int S, int D, int C, int L) {
  int t = blockIdx.x * blockDim.x + threadIdx.x;  // over B*C*D
  int d = t % D;
  int c = (t / D) % C;
  int b = t / (D * C);
  float w = -__expf(td[d]);
  float tfd = tfirst[d];
  int o = (b * C + c) * D + d;
  float num = inN[o], den = inD[o], m = inM[o];
  long long base = ((long long)(b * S + c * L)) * D + d;
  for (int i = 0; i < L; ++i) {
    float kk = bf2f(kb[base]);
    float vv = bf2f(vb[base]);
    float rv = bf2f(rb[base]);
    float ktf = kk + tfd;
    float mo = fmaxf(m, ktf);
    float e1 = __expf(m - mo);
    float e2 = __expf(ktf - mo);
    float out = (e1 * num + e2 * vv) / (e1 * den + e2);
    rr[base] = f2bf(out * rv);
    float mn = fmaxf(m + w, kk);
    e1 = __expf(m + w - mn);
    e2 = __expf(kk - mn);
    num = e1 * num + e2 * vv;
    den = e1 * den + e2;
    m = mn;
    base += D;
  }
}

// ---------------- launch ----------------
// NEW workspace/dispatch plan (9 dispatches, convs hoisted off critical path):
//   ws:    Wb4 [0,32) = {Wk_b,Wv_b,Wr_b,Wo_b} | Y=xv [32,64) | Z=xr [64,96)
//          | states [96,102)                               (102 MiB <= 110)
//   d_out: kb [0,32) | xk -> vb [32,64) | final fp32 [0,64)
// Sequential-disjointness per dispatch:
//   conv4:  inputs Wk..Wo (d_in) -> Wb4.
//   prep:   hidden -> xk (d_out hi), xv (Y), xr (Z).
//   gemm k: reads xk (d_out hi) + Wb[0] -> writes kb (d_out lo).   disjoint.
//   gemm v: reads Y + Wb[1]     -> writes vb (d_out hi).  xk consumed.
//   gemm r: reads Z + Wb[2]     -> writes rb (ws Y region). xv consumed.
//   scan1/2: read kb, vb -> states.
//   scan3:  reads kb, vb, rb -> writes rr (ws Z region). xr consumed.
//   gemm o: reads rr + Wb[3]    -> writes d_out fp32. kb/vb consumed.

extern "C" void kernel_launch(void* const* d_in, const int* in_sizes, int n_in,
                              void* d_out, int out_size, void* d_ws, size_t ws_size,
                              hipStream_t stream) {
  const float* hidden = (const float*)d_in[0];
  const float* td  = (const float*)d_in[1];
  const float* tfi = (const float*)d_in[2];
  const float* tmk = (const float*)d_in[3];
  const float* tmv = (const float*)d_in[4];
  const float* tmr = (const float*)d_in[5];
  const float* Wk  = (const float*)d_in[6];
  const float* Wv  = (const float*)d_in[7];
  const float* Wr  = (const float*)d_in[8];
  const float* Wo  = (const float*)d_in[9];
  float* out = (float*)d_out;

  const int H = in_sizes[1];                 // 2048
  const int D = H;
  const long long BS = (long long)in_sizes[0] / H;  // 8192 = B*S
  const int S = 2048;
  const int B = (int)(BS / S);               // 4
  const int C = 32, L = S / C;               // 32 chunks of 64

  char* ws = (char*)d_ws;
  const size_t MB = 1u << 20;
  unsigned short* Wb  = (unsigned short*)(ws + 0 * MB);    // 4 x 8 MiB
  unsigned short* Y   = (unsigned short*)(ws + 32 * MB);   // xv, later rb
  unsigned short* Z   = (unsigned short*)(ws + 64 * MB);   // xr, later rr
  float* locN         = (float*)(ws + 96 * MB);
  float* locD         = (float*)(ws + 97 * MB);
  float* locM         = (float*)(ws + 98 * MB);
  float* inN          = (float*)(ws + 99 * MB);
  float* inD          = (float*)(ws + 100 * MB);
  float* inM          = (float*)(ws + 101 * MB);

  unsigned short* kb  = (unsigned short*)d_out;                    // bf16 k
  unsigned short* xk  = (unsigned short*)((char*)d_out + 32 * MB); // then vb
  unsigned short* vb  = xk;
  unsigned short* rb  = Y;
  unsigned short* rr  = Z;

  const long long HH = (long long)H * H;     // 4194304 shorts = 8 MiB
  int n4w = H * H / 4;
  int cbk = (n4w + 255) / 256;
  long long total4 = BS * H / 4;
  int pbk = (int)((total4 + 255) / 256);
  int nwg = (int)((BS / 128) * (D / 256));   // 64 * 8 = 512 blocks, 2/CU

  // all 4 weight conversions, one dispatch, off the gemm critical path
  conv_bf16_4<<<dim3(cbk, 4), 256, 0, stream>>>(
      (const float4*)Wk, (const float4*)Wv, (const float4*)Wr, (const float4*)Wo,
      (ushort4*)Wb, n4w);

  // fused time-shift mix (one pass over hidden)
  prep_mix3<<<pbk, 256, 0, stream>>>((const float4*)hidden,
                                     (const float4*)tmk, (const float4*)tmv, (const float4*)tmr,
                                     (ushort4*)xk, (ushort4*)Y, (ushort4*)Z, S, H / 4, total4);

  // k = xk @ Wk^T ; v = xv @ Wv^T ; r = sigmoid(xr @ Wr^T)
  gemm_bt<2><<<nwg, 512, 0, stream>>>(xk, Wb + 0 * HH, nullptr, kb, (int)BS, D, H);
  gemm_bt<2><<<nwg, 512, 0, stream>>>(Y,  Wb + 1 * HH, nullptr, vb, (int)BS, D, H);
  gemm_bt<1><<<nwg, 512, 0, stream>>>(Z,  Wb + 2 * HH, nullptr, rb, (int)BS, D, H);

  // chunked WKV scan, fused r * rwkv -> rr (bf16)
  int nscan = B * C * D;
  scan_phase1<<<nscan / 256, 256, 0, stream>>>(kb, vb, td, locN, locD, locM, S, D, C, L);
  scan_phase2<<<(B * D + 255) / 256, 256, 0, stream>>>(td, locN, locD, locM, inN, inD, inM, B, D, C, L);
  scan_phase3<<<nscan / 256, 256, 0, stream>>>(kb, vb, rb, td, tfi, inN, inD, inM, rr, S, D, C, L);

  // out = (r * rwkv) @ Wo^T  (fp32 -> d_out; kb/vb dead now)
  gemm_bt<0><<<nwg, 512, 0, stream>>>(rr, Wb + 3 * HH, out, nullptr, (int)BS, H, D);
}